// Round 4
// baseline (254.843 us; speedup 1.0000x reference)
//
#include <hip/hip_runtime.h>
#include <hip/hip_bf16.h>

#define NROWS 8192
#define DIM 256
#define NSPLIT 32
#define JSPAN (NROWS / NSPLIT)   /* 256 cols per block */
#define BN 32
#define NT (JSPAN / BN)          /* 8 tiles per block */
#define RPW 64                   /* rows per wave (A stationary) */
#define RPB 256                  /* rows per block (4 waves) */
#define TILE_BYTES (BN * 512)    /* 16 KB */

typedef __bf16 bf16x8 __attribute__((ext_vector_type(8)));
typedef float f32x4 __attribute__((ext_vector_type(4)));

#define NEG_LOG2E -1.4426950408889634f
#define NEG_LN2   -0.6931471805599453f

// ---- Kernel 1: L2-normalize rows of both inputs, fp32 -> bf16; zero accums ----
// En rows are additionally scaled by -log2(e) so the GEMM directly produces
// acc = -log2e * sim  ->  exp(-sim) = exp2(acc), saving one VALU mul/element.
__global__ __launch_bounds__(256) void k_normalize_all(const float* __restrict__ emb,
                                                       const float* __restrict__ qry,
                                                       __hip_bfloat16* __restrict__ En,
                                                       __hip_bfloat16* __restrict__ Qn,
                                                       float* __restrict__ rowsum,
                                                       float* __restrict__ out) {
    // Fold the accumulator zeroing into this kernel (saves a memset launch).
    if (blockIdx.x < 8)
        reinterpret_cast<float4*>(rowsum)[blockIdx.x * 256 + threadIdx.x] =
            float4{0.f, 0.f, 0.f, 0.f};
    if (blockIdx.x == 8 && threadIdx.x == 0) out[0] = 0.f;

    const int gr   = blockIdx.x * 4 + (threadIdx.x >> 6);
    const int lane = threadIdx.x & 63;
    const float* in;
    __hip_bfloat16* outp;
    int row;
    float scale;
    if (gr < NROWS) { in = emb; outp = En; row = gr;         scale = NEG_LOG2E; }
    else            { in = qry; outp = Qn; row = gr - NROWS; scale = 1.0f; }
    const float4 v = reinterpret_cast<const float4*>(in + (size_t)row * DIM)[lane];
    float ss = v.x * v.x + v.y * v.y + v.z * v.z + v.w * v.w;
#pragma unroll
    for (int m = 32; m >= 1; m >>= 1) ss += __shfl_xor(ss, m, 64);
    const float inv = scale / fmaxf(sqrtf(ss), 1e-8f);
    __hip_bfloat16 o[4];
    o[0] = __float2bfloat16(v.x * inv);
    o[1] = __float2bfloat16(v.y * inv);
    o[2] = __float2bfloat16(v.z * inv);
    o[3] = __float2bfloat16(v.w * inv);
    reinterpret_cast<ushort4*>(outp + (size_t)row * DIM)[lane] = *reinterpret_cast<const ushort4*>(o);
}

// Stage half (g=0,1) of one BN x DIM bf16 tile (16 KB) into LDS, width-16 DMA.
// LDS dest linear; swizzle applied on SOURCE address (involution XOR), ds_read
// applies the same XOR (both-sides rule, G21).
__device__ __forceinline__ void stage_half(const char* __restrict__ gbase,
                                           char* lbase, int tid, int g) {
    const int wbase = tid & 192;
    const int lane  = tid & 63;
#pragma unroll
    for (int rr = 2 * g; rr < 2 * g + 2; ++rr) {
        const int id  = rr * 256 + wbase + lane;   // chunk 0..1023
        const int c   = id >> 5;                   // local col 0..31
        const int off = (id & 31) * 16;            // byte in col's 512B row
        const char* src = gbase + c * 512 + (off ^ ((c & 7) << 4));
        char* dst = lbase + (rr * 256 + wbase) * 16;   // wave-uniform base
        __builtin_amdgcn_global_load_lds(
            (const __attribute__((address_space(1))) void*)src,
            (__attribute__((address_space(3))) void*)dst, 16, 0, 0);
    }
}

// ---- Kernel 2: fused sim-GEMM + row sum of exp(-s) ----
// Grid: 32 i-blocks x 32 j-splits = 1024 blocks = 4 blocks/CU (the occupancy
// lever this round: 4 independent waves/SIMD to overlap ds/MFMA/VALU phases).
// Ring-2 LDS (32 KB/block); prefetch of tile t+1 issued during tile t's
// phases, so the boundary wait covers loads issued ~600+ cycles earlier.
__global__ __launch_bounds__(256, 4) void k_simlse(const __hip_bfloat16* __restrict__ En,
                                                   const __hip_bfloat16* __restrict__ Qn,
                                                   float* __restrict__ rowsum,
                                                   float* __restrict__ pickv) {
    __shared__ char lds[2][TILE_BYTES];   // 32 KB ring
    const int bx   = blockIdx.x;
    const int ib   = bx >> 5;
    const int jq   = bx & 31;
    const int tid  = threadIdx.x;
    const int lane = tid & 63;
    const int w    = tid >> 6;
    const int l15  = lane & 15;
    const int lks  = lane >> 4;          // k-segment 0..3
    const int i0w  = ib * RPB + w * RPW;

    // A fragments: 64 rows x K=256 -> a[4][8] (128 regs).
    bf16x8 a[4][8];
    {
        const __hip_bfloat16* ab = En + (size_t)(i0w + l15) * DIM + lks * 8;
#pragma unroll
        for (int mi = 0; mi < 4; ++mi)
#pragma unroll
            for (int kk = 0; kk < 8; ++kk)
                a[mi][kk] = *reinterpret_cast<const bf16x8*>(ab + mi * 16 * DIM + kk * 32);
    }

    float racc[4][4];
#pragma unroll
    for (int mi = 0; mi < 4; ++mi)
#pragma unroll
        for (int r = 0; r < 4; ++r) racc[mi][r] = 0.0f;

    const char* qbase = (const char*)Qn + (size_t)jq * JSPAN * 512;

    // Prologue: stage tile 0 fully, wait, barrier.
    stage_half(qbase, lds[0], tid, 0);
    stage_half(qbase, lds[0], tid, 1);
    asm volatile("s_waitcnt vmcnt(0)" ::: "memory");
    __builtin_amdgcn_s_barrier();
    __builtin_amdgcn_sched_barrier(0);

    for (int t = 0; t < NT; ++t) {
        const char* cur    = lds[t & 1];
        char* nbuf         = lds[(t + 1) & 1];
        const int jbase    = jq * JSPAN + t * BN;
        const bool spec    = (jbase <= i0w + RPW) && (jbase + BN > i0w);
        const char* nstage = qbase + (size_t)(t + 1) * TILE_BYTES;

#pragma unroll
        for (int g = 0; g < 2; ++g) {
            // Phase g: ds_read 16-col group, issue 2 DMA loads of tile t+1,
            // MFMA under setprio, exp2 epilogue.
            const int cl   = g * 16 + l15;
            const char* cb = cur + cl * 512;
            const int swz  = (cl & 7) << 4;
            bf16x8 b[8];
#pragma unroll
            for (int kk = 0; kk < 8; ++kk)
                b[kk] = *reinterpret_cast<const bf16x8*>(cb + ((kk * 64 + lks * 16) ^ swz));

            if (t + 1 < NT) stage_half(nstage, nbuf, tid, g);

            f32x4 acc[4];
#pragma unroll
            for (int mi = 0; mi < 4; ++mi) acc[mi] = f32x4{0.f, 0.f, 0.f, 0.f};

            __builtin_amdgcn_s_setprio(1);
#pragma unroll
            for (int kk = 0; kk < 8; ++kk)
#pragma unroll
                for (int mi = 0; mi < 4; ++mi)
                    acc[mi] = __builtin_amdgcn_mfma_f32_16x16x32_bf16(
                        a[mi][kk], b[kk], acc[mi], 0, 0, 0);
            __builtin_amdgcn_s_setprio(0);

            // Epilogue. acc = -log2e*s; exp(-s) = exp2(acc).
            // C/D layout: col = lane&15, row = (lane>>4)*4 + r.
            if (!spec) {
#pragma unroll
                for (int mi = 0; mi < 4; ++mi)
#pragma unroll
                    for (int r = 0; r < 4; ++r)
                        racc[mi][r] += __builtin_amdgcn_exp2f(acc[mi][r]);
            } else {
                const int jg = jbase + g * 16 + l15;
#pragma unroll
                for (int mi = 0; mi < 4; ++mi) {
                    const int ig0 = i0w + mi * 16 + lks * 4;
#pragma unroll
                    for (int r = 0; r < 4; ++r) {
                        const float e  = __builtin_amdgcn_exp2f(acc[mi][r]);
                        const int   ig = ig0 + r;
                        racc[mi][r] += (jg == ig) ? 0.0f : e;
                        const int pc = (ig == NROWS - 1) ? (NROWS - 2) : (ig + 1);
                        if (jg == pc) pickv[ig] = acc[mi][r] * NEG_LN2;  // recover s
                    }
                }
            }
        }

        if (t < NT - 1) {
            // All outstanding loads are tile t+1's 4 (issued 1-2 phases ago).
            asm volatile("s_waitcnt vmcnt(0)" ::: "memory");
            __builtin_amdgcn_s_barrier();
            __builtin_amdgcn_sched_barrier(0);
        }
    }

    // Reduce row partials across the 16 col-lanes, one atomicAdd per row.
#pragma unroll
    for (int mi = 0; mi < 4; ++mi)
#pragma unroll
        for (int r = 0; r < 4; ++r) {
            float v = racc[mi][r];
            v += __shfl_xor(v, 1, 64);
            v += __shfl_xor(v, 2, 64);
            v += __shfl_xor(v, 4, 64);
            v += __shfl_xor(v, 8, 64);
            if (l15 == 0) atomicAdd(&rowsum[i0w + mi * 16 + lks * 4 + r], v);
        }
}

// ---- Kernel 3: final reduce, 16 blocks, one atomicAdd each (out pre-zeroed) ----
__global__ __launch_bounds__(256) void k_finalize(const float* __restrict__ rowsum,
                                                  const float* __restrict__ pickv,
                                                  float* __restrict__ out) {
    __shared__ float red[4];
    const int base = blockIdx.x * 512;
    float s = 0.0f;
#pragma unroll
    for (int it = 0; it < 2; ++it) {
        const int i = base + it * 256 + threadIdx.x;
        s += __logf(rowsum[i]) + pickv[i];
    }
#pragma unroll
    for (int m = 32; m >= 1; m >>= 1) s += __shfl_xor(s, m, 64);
    if ((threadIdx.x & 63) == 0) red[threadIdx.x >> 6] = s;
    __syncthreads();
    if (threadIdx.x == 0)
        atomicAdd(out, (red[0] + red[1] + red[2] + red[3]) * (1.0f / (float)NROWS));
}

extern "C" void kernel_launch(void* const* d_in, const int* in_sizes, int n_in,
                              void* d_out, int out_size, void* d_ws, size_t ws_size,
                              hipStream_t stream) {
    const float* emb = (const float*)d_in[0];
    const float* qry = (const float*)d_in[1];
    float* out = (float*)d_out;

    char* ws = (char*)d_ws;
    __hip_bfloat16* En = (__hip_bfloat16*)ws;                                  // 4 MB
    __hip_bfloat16* Qn = (__hip_bfloat16*)(ws + (size_t)NROWS * DIM * 2);      // 4 MB
    float* rowsum = (float*)(ws + (size_t)NROWS * DIM * 4);                    // 32 KB
    float* pickv  = rowsum + NROWS;                                            // 32 KB

    k_normalize_all<<<2 * NROWS / 4, 256, 0, stream>>>(emb, qry, En, Qn, rowsum, out);
    k_simlse<<<32 * NSPLIT, 256, 0, stream>>>(En, Qn, rowsum, pickv);
    k_finalize<<<16, 256, 0, stream>>>(rowsum, pickv, out);
}

// Round 6
// 56.118 us; speedup vs baseline: 4.5412x; 4.5412x over previous
//
#include <hip/hip_runtime.h>
#include <hip/hip_bf16.h>

#define NROWS 8192
#define DIM 256
#define NSPLIT 16
#define JSPAN (NROWS / NSPLIT)   /* 512 cols per block */
#define BN 32
#define NT (JSPAN / BN)          /* 16 tiles per block */
#define RPW 64                   /* rows per wave (A stationary) */
#define RPB 256                  /* rows per block (4 waves) */
#define TILE_BYTES (BN * 512)    /* 16 KB */

typedef __bf16 bf16x8 __attribute__((ext_vector_type(8)));
typedef float f32x4 __attribute__((ext_vector_type(4)));

#define NEG_LOG2E -1.4426950408889634f
#define NEG_LN2   -0.6931471805599453f

// ---- Kernel 1: L2-normalize rows of both inputs, fp32 -> bf16; zero accums ----
// En rows are additionally scaled by -log2(e) so the GEMM directly produces
// acc = -log2e * sim  ->  exp(-sim) = exp2(acc).
__global__ __launch_bounds__(256) void k_normalize_all(const float* __restrict__ emb,
                                                       const float* __restrict__ qry,
                                                       __hip_bfloat16* __restrict__ En,
                                                       __hip_bfloat16* __restrict__ Qn,
                                                       float* __restrict__ rowsum,
                                                       float* __restrict__ out) {
    if (blockIdx.x < 8)
        reinterpret_cast<float4*>(rowsum)[blockIdx.x * 256 + threadIdx.x] =
            float4{0.f, 0.f, 0.f, 0.f};
    if (blockIdx.x == 8 && threadIdx.x == 0) out[0] = 0.f;

    const int gr   = blockIdx.x * 4 + (threadIdx.x >> 6);
    const int lane = threadIdx.x & 63;
    const float* in;
    __hip_bfloat16* outp;
    int row;
    float scale;
    if (gr < NROWS) { in = emb; outp = En; row = gr;         scale = NEG_LOG2E; }
    else            { in = qry; outp = Qn; row = gr - NROWS; scale = 1.0f; }
    const float4 v = reinterpret_cast<const float4*>(in + (size_t)row * DIM)[lane];
    float ss = v.x * v.x + v.y * v.y + v.z * v.z + v.w * v.w;
#pragma unroll
    for (int m = 32; m >= 1; m >>= 1) ss += __shfl_xor(ss, m, 64);
    const float inv = scale / fmaxf(sqrtf(ss), 1e-8f);
    __hip_bfloat16 o[4];
    o[0] = __float2bfloat16(v.x * inv);
    o[1] = __float2bfloat16(v.y * inv);
    o[2] = __float2bfloat16(v.z * inv);
    o[3] = __float2bfloat16(v.w * inv);
    reinterpret_cast<ushort4*>(outp + (size_t)row * DIM)[lane] = *reinterpret_cast<const ushort4*>(o);
}

// Stage half (g=0,1) of one BN x DIM bf16 tile (16 KB) into LDS, width-16 DMA.
// LDS dest linear; swizzle applied on SOURCE address (involution XOR), ds_read
// applies the same XOR (both-sides rule, G21).
__device__ __forceinline__ void stage_half(const char* __restrict__ gbase,
                                           char* lbase, int tid, int g) {
    const int wbase = tid & 192;
    const int lane  = tid & 63;
#pragma unroll
    for (int rr = 2 * g; rr < 2 * g + 2; ++rr) {
        const int id  = rr * 256 + wbase + lane;   // chunk 0..1023
        const int c   = id >> 5;                   // local col 0..31
        const int off = (id & 31) * 16;            // byte in col's 512B row
        const char* src = gbase + c * 512 + (off ^ ((c & 7) << 4));
        char* dst = lbase + (rr * 256 + wbase) * 16;   // wave-uniform base
        __builtin_amdgcn_global_load_lds(
            (const __attribute__((address_space(1))) void*)src,
            (__attribute__((address_space(3))) void*)dst, 16, 0, 0);
    }
}

// ---- Kernel 2: fused sim-GEMM + row sum of exp(-s) ----
// 4 waves/block, 64 stationary A-rows per wave (a[4][8], 128 VGPR), LDS Q-tile
// shared by the 4 waves. Ring-4 LDS, stage-ahead-2, counted vmcnt(4) (T4).
// The exp2 epilogue is software-pipelined one phase back (static accA/accB
// double-buffer, T15) so it runs on the VALU while the ds reads of the
// current phase are in flight, and the matrix pipe never waits for it.
__global__ __launch_bounds__(256, 2) void k_simlse(const __hip_bfloat16* __restrict__ En,
                                                   const __hip_bfloat16* __restrict__ Qn,
                                                   float* __restrict__ rowsum,
                                                   float* __restrict__ pickv) {
    __shared__ char lds[4][TILE_BYTES];   // 64 KB ring
    const int bx   = blockIdx.x;
    const int ib   = bx >> 4;
    const int jq   = bx & 15;
    const int tid  = threadIdx.x;
    const int lane = tid & 63;
    const int w    = tid >> 6;
    const int l15  = lane & 15;
    const int lks  = lane >> 4;          // k-segment 0..3
    const int i0w  = ib * RPB + w * RPW;

    // A fragments: 64 rows x K=256 -> a[4][8] (128 regs).
    bf16x8 a[4][8];
    {
        const __hip_bfloat16* ab = En + (size_t)(i0w + l15) * DIM + lks * 8;
#pragma unroll
        for (int mi = 0; mi < 4; ++mi)
#pragma unroll
            for (int kk = 0; kk < 8; ++kk)
                a[mi][kk] = *reinterpret_cast<const bf16x8*>(ab + mi * 16 * DIM + kk * 32);
    }

    float racc[4][4];
#pragma unroll
    for (int mi = 0; mi < 4; ++mi)
#pragma unroll
        for (int r = 0; r < 4; ++r) racc[mi][r] = 0.0f;

    const char* qbase = (const char*)Qn + (size_t)jq * JSPAN * 512;

    // Deferred epilogue. acc = -log2e*s; exp(-s) = exp2(acc).
    // C/D layout: col = lane&15, row = (lane>>4)*4 + r.
    auto do_ep = [&](const f32x4 (&acc)[4], int epJg, bool epSpec) {
        if (!epSpec) {
#pragma unroll
            for (int mi = 0; mi < 4; ++mi)
#pragma unroll
                for (int r = 0; r < 4; ++r)
                    racc[mi][r] += __builtin_amdgcn_exp2f(acc[mi][r]);
        } else {
#pragma unroll
            for (int mi = 0; mi < 4; ++mi) {
                const int ig0 = i0w + mi * 16 + lks * 4;
#pragma unroll
                for (int r = 0; r < 4; ++r) {
                    const float e  = __builtin_amdgcn_exp2f(acc[mi][r]);
                    const int   ig = ig0 + r;
                    racc[mi][r] += (epJg == ig) ? 0.0f : e;
                    const int pc = (ig == NROWS - 1) ? (NROWS - 2) : (ig + 1);
                    if (epJg == pc) pickv[ig] = acc[mi][r] * NEG_LN2;  // recover s
                }
            }
        }
    };

    // One phase: ds_read B-group (t,g); issue DMA for tile t+2 half g; run the
    // PREVIOUS phase's epilogue (hides ds latency, VALU || matrix); MFMA.
    auto phase = [&](int t, int g, f32x4 (&accOut)[4], bool doEp,
                     const f32x4 (&accEp)[4], int epJg, bool epSpec) {
        const char* cur = lds[t & 3];
        const int cl    = g * 16 + l15;
        const char* cb  = cur + cl * 512;
        const int swz   = (cl & 7) << 4;
        bf16x8 b[8];
#pragma unroll
        for (int kk = 0; kk < 8; ++kk)
            b[kk] = *reinterpret_cast<const bf16x8*>(cb + ((kk * 64 + lks * 16) ^ swz));

        if (t + 2 < NT)
            stage_half(qbase + (size_t)(t + 2) * TILE_BYTES, lds[(t + 2) & 3], tid, g);

        if (doEp) do_ep(accEp, epJg, epSpec);

#pragma unroll
        for (int mi = 0; mi < 4; ++mi) accOut[mi] = f32x4{0.f, 0.f, 0.f, 0.f};

        __builtin_amdgcn_sched_barrier(0);   // keep epilogue before the MFMAs
        __builtin_amdgcn_s_setprio(1);
#pragma unroll
        for (int kk = 0; kk < 8; ++kk)
#pragma unroll
            for (int mi = 0; mi < 4; ++mi)
                accOut[mi] = __builtin_amdgcn_mfma_f32_16x16x32_bf16(
                    a[mi][kk], b[kk], accOut[mi], 0, 0, 0);
        __builtin_amdgcn_s_setprio(0);
    };

    // Prologue: stage tiles 0 and 1; tile 1's 4 loads may stay in flight.
    stage_half(qbase, lds[0], tid, 0);
    stage_half(qbase, lds[0], tid, 1);
    stage_half(qbase + TILE_BYTES, lds[1], tid, 0);
    stage_half(qbase + TILE_BYTES, lds[1], tid, 1);
    asm volatile("s_waitcnt vmcnt(4)" ::: "memory");
    __builtin_amdgcn_s_barrier();
    __builtin_amdgcn_sched_barrier(0);

    f32x4 accA[4], accB[4];
    const int jq0 = jq * JSPAN;

    // Peeled first phase (0,0): no epilogue yet.
    phase(0, 0, accA, false, accB, 0, false);

    for (int t = 0; t < NT; ++t) {
        const int jbase = jq0 + t * BN;
        const bool spec = (jbase <= i0w + RPW) && (jbase + BN > i0w);

        // Phase (t,1): MFMA into accB, epilogue of phase (t,0) from accA.
        phase(t, 1, accB, true, accA, jbase + l15, spec);

        if (t < NT - 1) {
            // Tile boundary: tile t+1 must be resident; tile t+2's 4 loads
            // (issued this tile) may stay in flight.
            if (t + 2 < NT) asm volatile("s_waitcnt vmcnt(4)" ::: "memory");
            else            asm volatile("s_waitcnt vmcnt(0)" ::: "memory");
            __builtin_amdgcn_s_barrier();
            __builtin_amdgcn_sched_barrier(0);

            // Phase (t+1,0): MFMA into accA, epilogue of phase (t,1) from accB.
            phase(t + 1, 0, accA, true, accB, jbase + 16 + l15, spec);
        }
    }

    // Drain the pipeline: epilogue of the last phase (NT-1, 1).
    {
        const int jbase = jq0 + (NT - 1) * BN;
        const bool spec = (jbase <= i0w + RPW) && (jbase + BN > i0w);
        do_ep(accB, jbase + 16 + l15, spec);
    }

    // Reduce row partials across the 16 col-lanes, one atomicAdd per row.
#pragma unroll
    for (int mi = 0; mi < 4; ++mi)
#pragma unroll
        for (int r = 0; r < 4; ++r) {
            float v = racc[mi][r];
            v += __shfl_xor(v, 1, 64);
            v += __shfl_xor(v, 2, 64);
            v += __shfl_xor(v, 4, 64);
            v += __shfl_xor(v, 8, 64);
            if (l15 == 0) atomicAdd(&rowsum[i0w + mi * 16 + lks * 4 + r], v);
        }
}

// ---- Kernel 3: final reduce, 16 blocks, one atomicAdd each (out pre-zeroed) ----
__global__ __launch_bounds__(256) void k_finalize(const float* __restrict__ rowsum,
                                                  const float* __restrict__ pickv,
                                                  float* __restrict__ out) {
    __shared__ float red[4];
    const int base = blockIdx.x * 512;
    float s = 0.0f;
#pragma unroll
    for (int it = 0; it < 2; ++it) {
        const int i = base + it * 256 + threadIdx.x;
        s += __logf(rowsum[i]) + pickv[i];
    }
#pragma unroll
    for (int m = 32; m >= 1; m >>= 1) s += __shfl_xor(s, m, 64);
    if ((threadIdx.x & 63) == 0) red[threadIdx.x >> 6] = s;
    __syncthreads();
    if (threadIdx.x == 0)
        atomicAdd(out, (red[0] + red[1] + red[2] + red[3]) * (1.0f / (float)NROWS));
}

extern "C" void kernel_launch(void* const* d_in, const int* in_sizes, int n_in,
                              void* d_out, int out_size, void* d_ws, size_t ws_size,
                              hipStream_t stream) {
    const float* emb = (const float*)d_in[0];
    const float* qry = (const float*)d_in[1];
    float* out = (float*)d_out;

    char* ws = (char*)d_ws;
    __hip_bfloat16* En = (__hip_bfloat16*)ws;                                  // 4 MB
    __hip_bfloat16* Qn = (__hip_bfloat16*)(ws + (size_t)NROWS * DIM * 2);      // 4 MB
    float* rowsum = (float*)(ws + (size_t)NROWS * DIM * 4);                    // 32 KB
    float* pickv  = rowsum + NROWS;                                            // 32 KB

    k_normalize_all<<<2 * NROWS / 4, 256, 0, stream>>>(emb, qry, En, Qn, rowsum, out);
    k_simlse<<<32 * NSPLIT, 256, 0, stream>>>(En, Qn, rowsum, pickv);
    k_finalize<<<16, 256, 0, stream>>>(rowsum, pickv, out);
}